// Round 10
// baseline (285.464 us; speedup 1.0000x reference)
//
#include <hip/hip_runtime.h>
#include <math.h>

#define N_NODES 10000
#define N_EDGES 320000
#define CAP 128        // max in-degree bucket capacity (mean 32, +17 sigma)
#define TN 8192        // gate table samples over [0, 8]; step = 1/1024
#define TSCALE 1024.0f // TN / 8
#define AI_BLOCKS 40   // 40*256 >= 10000 nodes
#define TB_BLOCKS 33   // 33*256 >= TN+1 table entries

__device__ __forceinline__ float silu_f(float x) {
    return x / (1.0f + __expf(-x));
}

// ---------------- kernel 1: prep = deg clear + node Ai MLP + gates(r) table ----
// Every path keeps live state <= ~30 floats: the occupancy-targeting register
// allocator (r2/r4: 48 VGPR, r9: 28 VGPR) can NEVER spill these.
__global__ __launch_bounds__(256) void prep_kernel(
    const float* __restrict__ atom_emb, const int* __restrict__ A,
    const float* __restrict__ w1, const float* __restrict__ b1,
    const float* __restrict__ w2, const float* __restrict__ b2,
    const float* __restrict__ fw1, const float* __restrict__ fb1,
    const float* __restrict__ fw2, const float* __restrict__ fb2,
    const float* __restrict__ fw3, const float* __restrict__ fb3,
    float* __restrict__ Ai, float4* __restrict__ tab, int* __restrict__ deg)
{
    int bid = blockIdx.x;
    if (bid < AI_BLOCKS) {
        int n = bid * 256 + threadIdx.x;
        if (n >= N_NODES) return;
        deg[n] = 0;                      // replaces the memset dispatch
        int a = A[n];
        float emb[16];
        #pragma unroll
        for (int i = 0; i < 16; ++i) emb[i] = atom_emb[a * 16 + i];
        float acc[8];
        #pragma unroll
        for (int o = 0; o < 8; ++o) acc[o] = b2[o];
        #pragma unroll 4
        for (int j = 0; j < 64; ++j) {
            float s0 = b1[j], s1 = 0.f;
            #pragma unroll
            for (int i = 0; i < 16; i += 2) {
                s0 += emb[i]     * w1[i * 64 + j];
                s1 += emb[i + 1] * w1[(i + 1) * 64 + j];
            }
            float h = silu_f(s0 + s1);
            #pragma unroll
            for (int o = 0; o < 8; ++o) acc[o] += h * w2[j * 8 + o];
        }
        #pragma unroll
        for (int o = 0; o < 8; ++o) Ai[n * 8 + o] = acc[o];
        return;
    }

    // ---- gates(r) table: t in [0, TN] inclusive ----
    // i-outer / j-eighth: recompute g1[i] per pass (10 FMA + silu), hold only
    // acc[8]. Peak live ~26 floats (r9 proved a 28-VGPR budget, so this fits).
    int t = (bid - AI_BLOCKS) * 256 + threadIdx.x;
    if (t > TN) return;
    float r = (float)t * (1.0f / TSCALE);

    float rb[10];
    {
        float x = r * 2.2f;
        #pragma unroll
        for (int i = 0; i < 10; ++i) {
            float d = x - (float)(i + 1);
            rb[i] = __expf(-d * d) * 2.8234622f;
        }
    }

    float gate0 = fb3[0], gate3 = fb3[3], gate9 = fb3[9];
    #pragma unroll 1
    for (int q = 0; q < 8; ++q) {
        float acc[8];
        #pragma unroll
        for (int j = 0; j < 8; ++j) acc[j] = fb2[q * 8 + j];
        #pragma unroll 1
        for (int i = 0; i < 64; ++i) {
            float s = fb1[i];
            #pragma unroll
            for (int k = 0; k < 10; ++k) s += rb[k] * fw1[k * 64 + i];
            float g1i = silu_f(s);
            const float* w2row = fw2 + i * 64 + q * 8;
            #pragma unroll
            for (int j = 0; j < 8; ++j) acc[j] += g1i * w2row[j];
        }
        #pragma unroll
        for (int j = 0; j < 8; ++j) {
            float h = silu_f(acc[j]);
            int jj = q * 8 + j;
            gate0 += h * fw3[jj * 15 + 0];
            gate3 += h * fw3[jj * 15 + 3];
            gate9 += h * fw3[jj * 15 + 9];
        }
    }
    tab[t] = make_float4(gate0, gate3, gate9, 0.f);
}

// ---------------- kernel 2: bucket insert with full edge-vector record ---------
// All inputs coalesced by e except the two 12B pos gathers (pos = 120KB, L2/L1
// resident). Scatters ONE 16B record (vx,vy,vz,src) per edge — same sector
// count as the old int2, but the gather then needs no shifts/batch/cell/pos.
__global__ __launch_bounds__(256) void bucket_kernel(
    const int* __restrict__ edge_src, const int* __restrict__ edge_dst,
    const float* __restrict__ pos, const float* __restrict__ edge_shifts,
    const float* __restrict__ cell, const int* __restrict__ batch,
    int* __restrict__ deg, float4* __restrict__ elist)
{
    int e = blockIdx.x * 256 + threadIdx.x;
    int dst = edge_dst[e];
    int src = edge_src[e];

    float s0 = edge_shifts[e * 3 + 0];
    float s1 = edge_shifts[e * 3 + 1];
    float s2 = edge_shifts[e * 3 + 2];

    float vx = pos[dst * 3 + 0] - pos[src * 3 + 0];
    float vy = pos[dst * 3 + 1] - pos[src * 3 + 1];
    float vz = pos[dst * 3 + 2] - pos[src * 3 + 2];

    if (s0 != 0.f || s1 != 0.f || s2 != 0.f) {   // wave-uniform false for zero shifts
        int b = batch[src];
        const float* Cb = cell + b * 9;
        vx += s0 * Cb[0] + s1 * Cb[3] + s2 * Cb[6];
        vy += s0 * Cb[1] + s1 * Cb[4] + s2 * Cb[7];
        vz += s0 * Cb[2] + s1 * Cb[5] + s2 * Cb[8];
    }

    int p = atomicAdd(&deg[dst], 1);
    if (p < CAP) {
        float4 rec = make_float4(vx, vy, vz, __int_as_float(src));
        elist[dst * CAP + p] = rec;
    }
}

// ---------------- kernel 3: fused gather + tp_w contraction + output ------------
// Block = 256 threads = 4 waves = 4 nodes; lane = slot*8 + u.
// Phase 1: each slot-group of 8 lanes processes one edge record: r from v,
//          table-lerp gates, Y harmonics, acc[k] += q[k]*Ai[src][u];
//          shfl-reduce over slots -> M[u][9] in LDS.
// Phase 2: 128 threads contract with tp_w and write out[n][288].
__global__ __launch_bounds__(256) void gather_out_kernel(
    const int* __restrict__ deg, const float4* __restrict__ elist,
    const float4* __restrict__ tab, const float* __restrict__ Ai,
    const float* __restrict__ tp_w, float* __restrict__ out)
{
    __shared__ float sM[4][72];
    __shared__ float sA[4][8];
    int tid = threadIdx.x;
    int lane = tid & 63;
    int wv = tid >> 6;
    int nodeBase = blockIdx.x * 4;
    int n1 = nodeBase + wv;
    int u1 = lane & 7;
    int slot = lane >> 3;

    int d = deg[n1];
    int dc = d > CAP ? CAP : d;

    const float SQ3 = 1.7320508075688772f;
    const float SQ15 = 3.872983346207417f;
    const float SQ5H = 1.1180339887498949f;   // sqrt(5)/2

    float acc[9];
    #pragma unroll
    for (int k = 0; k < 9; ++k) acc[k] = 0.f;

    const float4* el = elist + n1 * CAP;
    for (int i = slot; i < dc; i += 8) {
        float4 rec = el[i];
        float vx = rec.x, vy = rec.y, vz = rec.z;
        int src = __float_as_int(rec.w);

        float r = sqrtf(vx * vx + vy * vy + vz * vz);
        float rinv = 1.0f / fmaxf(r, 1e-8f);
        float nx = vx * rinv, ny = vy * rinv, nz = vz * rinv;

        float tf = fminf(r * TSCALE, (float)(TN - 1));
        int   i0 = (int)tf;
        float fr = tf - (float)i0;
        float4 ga = tab[i0];
        float4 gb = tab[i0 + 1];
        float gate0 = ga.x + fr * (gb.x - ga.x);
        float gate3 = ga.y + fr * (gb.y - ga.y);
        float gate9 = ga.z + fr * (gb.z - ga.z);

        float au = Ai[src * 8 + u1];

        acc[0] += gate0 * au;
        float g3a = gate3 * au;
        acc[1] += g3a * (SQ3 * nx);
        acc[2] += g3a * (SQ3 * ny);
        acc[3] += g3a * (SQ3 * nz);
        float g9a = gate9 * au;
        acc[4] += g9a * (SQ15 * nx * ny);
        acc[5] += g9a * (SQ15 * ny * nz);
        acc[6] += g9a * (SQ5H * (3.0f * nz * nz - 1.0f));
        acc[7] += g9a * (SQ15 * nx * nz);
        acc[8] += g9a * (0.5f * SQ15 * (nx * nx - ny * ny));
    }

    #pragma unroll
    for (int m = 8; m < 64; m <<= 1) {
        #pragma unroll
        for (int k = 0; k < 9; ++k) acc[k] += __shfl_xor(acc[k], m, 64);
    }

    if (slot == 0) {
        #pragma unroll
        for (int k = 0; k < 9; ++k) sM[wv][u1 * 9 + k] = acc[k];
    }
    if (tid < 32) sA[tid >> 3][tid & 7] = Ai[nodeBase * 8 + tid];
    __syncthreads();

    if (tid >= 128) return;
    int ln = tid >> 5, w = tid & 31;
    int n = nodeBase + ln;

    float a[8];
    #pragma unroll
    for (int v = 0; v < 8; ++v) a[v] = sA[ln][v];
    float inv = 1.0f / fmaxf((float)deg[n], 1.0f);

    const float* W0 = tp_w + 0 * 2048;   // path (0,0,0)
    const float* W3 = tp_w + 3 * 2048;   // path (1,0,1)
    const float* W9 = tp_w + 9 * 2048;   // path (2,0,2)

    // l=0 block (32 floats at offset 0)
    {
        float o0 = 0.f;
        #pragma unroll
        for (int u = 0; u < 8; ++u) {
            float c = 0.f;
            #pragma unroll
            for (int v = 0; v < 8; ++v) c += a[v] * W0[(u * 8 + v) * 32 + w];
            o0 += sM[ln][u * 9] * c;
        }
        out[n * 288 + w] = o0 * inv;
    }
    // l=1 block (96 floats at offset 32), layout [w][k], k<3
    {
        float o1[3] = {0.f, 0.f, 0.f};
        #pragma unroll
        for (int u = 0; u < 8; ++u) {
            float c = 0.f;
            #pragma unroll
            for (int v = 0; v < 8; ++v) c += a[v] * W3[(u * 8 + v) * 32 + w];
            #pragma unroll
            for (int k = 0; k < 3; ++k) o1[k] += sM[ln][u * 9 + 1 + k] * c;
        }
        #pragma unroll
        for (int k = 0; k < 3; ++k) out[n * 288 + 32 + w * 3 + k] = o1[k] * inv;
    }
    // l=2 block (160 floats at offset 128), layout [w][k], k<5
    {
        float o2[5] = {0.f, 0.f, 0.f, 0.f, 0.f};
        #pragma unroll
        for (int u = 0; u < 8; ++u) {
            float c = 0.f;
            #pragma unroll
            for (int v = 0; v < 8; ++v) c += a[v] * W9[(u * 8 + v) * 32 + w];
            #pragma unroll
            for (int k = 0; k < 5; ++k) o2[k] += sM[ln][u * 9 + 4 + k] * c;
        }
        #pragma unroll
        for (int k = 0; k < 5; ++k) out[n * 288 + 128 + w * 5 + k] = o2[k] * inv;
    }
}

// ---------------- launch ---------------------------------------------------------
extern "C" void kernel_launch(void* const* d_in, const int* in_sizes, int n_in,
                              void* d_out, int out_size, void* d_ws, size_t ws_size,
                              hipStream_t stream) {
    const float* pos         = (const float*)d_in[0];
    const float* edge_shifts = (const float*)d_in[1];
    const float* cell        = (const float*)d_in[2];
    const float* atom_emb    = (const float*)d_in[3];
    const float* mlp_w1      = (const float*)d_in[4];
    const float* mlp_b1      = (const float*)d_in[5];
    const float* mlp_w2      = (const float*)d_in[6];
    const float* mlp_b2      = (const float*)d_in[7];
    const float* fc_w1       = (const float*)d_in[8];
    const float* fc_b1       = (const float*)d_in[9];
    const float* fc_w2       = (const float*)d_in[10];
    const float* fc_b2       = (const float*)d_in[11];
    const float* fc_w3       = (const float*)d_in[12];
    const float* fc_b3       = (const float*)d_in[13];
    const float* tp_w        = (const float*)d_in[14];
    const int*   A           = (const int*)d_in[15];
    const int*   batch       = (const int*)d_in[16];
    const int*   edge_src    = (const int*)d_in[17];
    const int*   edge_dst    = (const int*)d_in[18];
    float* out = (float*)d_out;

    // workspace layout (16B aligned):
    // float4 elist[10000*128] | float Ai[80000] | float4 tab[TN+1] | int deg[10000]
    float4* elist = (float4*)d_ws;
    float*  Ai    = (float*)(elist + (size_t)N_NODES * CAP);
    float4* tab   = (float4*)(Ai + N_NODES * 8);
    int*    deg   = (int*)(tab + (TN + 1));
    // total: ~21 MB

    prep_kernel<<<AI_BLOCKS + TB_BLOCKS, 256, 0, stream>>>(
        atom_emb, A, mlp_w1, mlp_b1, mlp_w2, mlp_b2,
        fc_w1, fc_b1, fc_w2, fc_b2, fc_w3, fc_b3, Ai, tab, deg);

    bucket_kernel<<<N_EDGES / 256, 256, 0, stream>>>(
        edge_src, edge_dst, pos, edge_shifts, cell, batch, deg, elist);

    gather_out_kernel<<<N_NODES / 4, 256, 0, stream>>>(
        deg, elist, tab, Ai, tp_w, out);
}

// Round 11
// 156.021 us; speedup vs baseline: 1.8297x; 1.8297x over previous
//
#include <hip/hip_runtime.h>
#include <math.h>

#define N_NODES 10000
#define N_EDGES 320000
#define CAP 128        // max in-degree bucket capacity (mean 32, +17 sigma)
#define TN 8192        // gate table samples over [0, 8]; step = 1/1024
#define TSCALE 1024.0f // TN / 8
#define AI_BLOCKS 40   // 40*256 >= 10000 nodes
#define TB_BLOCKS 2049 // ceil((TN+1)/4) wave-per-entry blocks

__device__ __forceinline__ float silu_f(float x) {
    return x / (1.0f + __expf(-x));
}

// ---------------- kernel 1: prep = deg clear + node Ai MLP + gates(r) table ----
// Table path is WAVE-PARALLEL: one wave per entry t, lane i owns g1[i], fc2 via
// __shfl broadcast, fc3 via shfl_xor reduce. No per-thread arrays beyond rb[10],
// no runtime serial loops over wave-uniform scalar loads (r10 lesson: 33 blocks
// of latency-chained s_loads ran at 1.6% occupancy for 150us).
__global__ __launch_bounds__(256) void prep_kernel(
    const float* __restrict__ atom_emb, const int* __restrict__ A,
    const float* __restrict__ w1, const float* __restrict__ b1,
    const float* __restrict__ w2, const float* __restrict__ b2,
    const float* __restrict__ fw1, const float* __restrict__ fb1,
    const float* __restrict__ fw2, const float* __restrict__ fb2,
    const float* __restrict__ fw3, const float* __restrict__ fb3,
    float* __restrict__ Ai, float4* __restrict__ tab, int* __restrict__ deg)
{
    int bid = blockIdx.x;
    if (bid < AI_BLOCKS) {
        int n = bid * 256 + threadIdx.x;
        if (n >= N_NODES) return;
        deg[n] = 0;                      // replaces the memset dispatch
        int a = A[n];
        float emb[16];
        #pragma unroll
        for (int i = 0; i < 16; ++i) emb[i] = atom_emb[a * 16 + i];
        float acc[8];
        #pragma unroll
        for (int o = 0; o < 8; ++o) acc[o] = b2[o];
        #pragma unroll 4
        for (int j = 0; j < 64; ++j) {
            float s0 = b1[j], s1 = 0.f;
            #pragma unroll
            for (int i = 0; i < 16; i += 2) {
                s0 += emb[i]     * w1[i * 64 + j];
                s1 += emb[i + 1] * w1[(i + 1) * 64 + j];
            }
            float h = silu_f(s0 + s1);
            #pragma unroll
            for (int o = 0; o < 8; ++o) acc[o] += h * w2[j * 8 + o];
        }
        #pragma unroll
        for (int o = 0; o < 8; ++o) Ai[n * 8 + o] = acc[o];
        return;
    }

    // ---- gates(r) table: one wave per entry ----
    int lane = threadIdx.x & 63;
    int t = (bid - AI_BLOCKS) * 4 + (threadIdx.x >> 6);
    if (t > TN) return;
    float r = (float)t * (1.0f / TSCALE);

    // rb (each lane computes its own copy; 10 exp, trivial)
    float rb[10];
    {
        float x = r * 2.2f;
        #pragma unroll
        for (int i = 0; i < 10; ++i) {
            float d = x - (float)(i + 1);
            rb[i] = __expf(-d * d) * 2.8234622f;
        }
    }

    // g1[lane] = silu(fc1): coalesced vector loads fw1[k*64+lane]
    float g1;
    {
        float s = fb1[lane];
        #pragma unroll
        for (int k = 0; k < 10; ++k) s += rb[k] * fw1[k * 64 + lane];
        g1 = silu_f(s);
    }

    // h[lane] = silu(fc2): g1 broadcast via shfl, fw2 coalesced
    float acc = fb2[lane];
    #pragma unroll 8
    for (int i = 0; i < 64; ++i) {
        float gi = __shfl(g1, i, 64);
        acc += gi * fw2[i * 64 + lane];
    }
    float h = silu_f(acc);

    // fc3 partials, wave reduce over j=lane
    float p0 = h * fw3[lane * 15 + 0];
    float p3 = h * fw3[lane * 15 + 3];
    float p9 = h * fw3[lane * 15 + 9];
    #pragma unroll
    for (int m = 1; m < 64; m <<= 1) {
        p0 += __shfl_xor(p0, m, 64);
        p3 += __shfl_xor(p3, m, 64);
        p9 += __shfl_xor(p9, m, 64);
    }
    if (lane == 0) {
        tab[t] = make_float4(fb3[0] + p0, fb3[3] + p3, fb3[9] + p9, 0.f);
    }
}

// ---------------- kernel 2: bucket insert with full edge-vector record ---------
// All inputs coalesced by e except the two 12B pos gathers (pos = 120KB, L2/L1
// resident). Scatters ONE 16B record (vx,vy,vz,src) per edge.
__global__ __launch_bounds__(256) void bucket_kernel(
    const int* __restrict__ edge_src, const int* __restrict__ edge_dst,
    const float* __restrict__ pos, const float* __restrict__ edge_shifts,
    const float* __restrict__ cell, const int* __restrict__ batch,
    int* __restrict__ deg, float4* __restrict__ elist)
{
    int e = blockIdx.x * 256 + threadIdx.x;
    int dst = edge_dst[e];
    int src = edge_src[e];

    float s0 = edge_shifts[e * 3 + 0];
    float s1 = edge_shifts[e * 3 + 1];
    float s2 = edge_shifts[e * 3 + 2];

    float vx = pos[dst * 3 + 0] - pos[src * 3 + 0];
    float vy = pos[dst * 3 + 1] - pos[src * 3 + 1];
    float vz = pos[dst * 3 + 2] - pos[src * 3 + 2];

    if (s0 != 0.f || s1 != 0.f || s2 != 0.f) {   // wave-uniform false for zero shifts
        int b = batch[src];
        const float* Cb = cell + b * 9;
        vx += s0 * Cb[0] + s1 * Cb[3] + s2 * Cb[6];
        vy += s0 * Cb[1] + s1 * Cb[4] + s2 * Cb[7];
        vz += s0 * Cb[2] + s1 * Cb[5] + s2 * Cb[8];
    }

    int p = atomicAdd(&deg[dst], 1);
    if (p < CAP) {
        elist[dst * CAP + p] = make_float4(vx, vy, vz, __int_as_float(src));
    }
}

// ---------------- kernel 3: fused gather + tp_w contraction + output ------------
// Block = 256 threads = 4 waves = 4 nodes; lane = slot*8 + u.
__global__ __launch_bounds__(256) void gather_out_kernel(
    const int* __restrict__ deg, const float4* __restrict__ elist,
    const float4* __restrict__ tab, const float* __restrict__ Ai,
    const float* __restrict__ tp_w, float* __restrict__ out)
{
    __shared__ float sM[4][72];
    __shared__ float sA[4][8];
    int tid = threadIdx.x;
    int lane = tid & 63;
    int wv = tid >> 6;
    int nodeBase = blockIdx.x * 4;
    int n1 = nodeBase + wv;
    int u1 = lane & 7;
    int slot = lane >> 3;

    int d = deg[n1];
    int dc = d > CAP ? CAP : d;

    const float SQ3 = 1.7320508075688772f;
    const float SQ15 = 3.872983346207417f;
    const float SQ5H = 1.1180339887498949f;   // sqrt(5)/2

    float acc[9];
    #pragma unroll
    for (int k = 0; k < 9; ++k) acc[k] = 0.f;

    const float4* el = elist + n1 * CAP;
    for (int i = slot; i < dc; i += 8) {
        float4 rec = el[i];
        float vx = rec.x, vy = rec.y, vz = rec.z;
        int src = __float_as_int(rec.w);

        float r = sqrtf(vx * vx + vy * vy + vz * vz);
        float rinv = 1.0f / fmaxf(r, 1e-8f);
        float nx = vx * rinv, ny = vy * rinv, nz = vz * rinv;

        float tf = fminf(r * TSCALE, (float)(TN - 1));
        int   i0 = (int)tf;
        float fr = tf - (float)i0;
        float4 ga = tab[i0];
        float4 gb = tab[i0 + 1];
        float gate0 = ga.x + fr * (gb.x - ga.x);
        float gate3 = ga.y + fr * (gb.y - ga.y);
        float gate9 = ga.z + fr * (gb.z - ga.z);

        float au = Ai[src * 8 + u1];

        acc[0] += gate0 * au;
        float g3a = gate3 * au;
        acc[1] += g3a * (SQ3 * nx);
        acc[2] += g3a * (SQ3 * ny);
        acc[3] += g3a * (SQ3 * nz);
        float g9a = gate9 * au;
        acc[4] += g9a * (SQ15 * nx * ny);
        acc[5] += g9a * (SQ15 * ny * nz);
        acc[6] += g9a * (SQ5H * (3.0f * nz * nz - 1.0f));
        acc[7] += g9a * (SQ15 * nx * nz);
        acc[8] += g9a * (0.5f * SQ15 * (nx * nx - ny * ny));
    }

    #pragma unroll
    for (int m = 8; m < 64; m <<= 1) {
        #pragma unroll
        for (int k = 0; k < 9; ++k) acc[k] += __shfl_xor(acc[k], m, 64);
    }

    if (slot == 0) {
        #pragma unroll
        for (int k = 0; k < 9; ++k) sM[wv][u1 * 9 + k] = acc[k];
    }
    if (tid < 32) sA[tid >> 3][tid & 7] = Ai[nodeBase * 8 + tid];
    __syncthreads();

    if (tid >= 128) return;
    int ln = tid >> 5, w = tid & 31;
    int n = nodeBase + ln;

    float a[8];
    #pragma unroll
    for (int v = 0; v < 8; ++v) a[v] = sA[ln][v];
    float inv = 1.0f / fmaxf((float)deg[n], 1.0f);

    const float* W0 = tp_w + 0 * 2048;   // path (0,0,0)
    const float* W3 = tp_w + 3 * 2048;   // path (1,0,1)
    const float* W9 = tp_w + 9 * 2048;   // path (2,0,2)

    // l=0 block (32 floats at offset 0)
    {
        float o0 = 0.f;
        #pragma unroll
        for (int u = 0; u < 8; ++u) {
            float c = 0.f;
            #pragma unroll
            for (int v = 0; v < 8; ++v) c += a[v] * W0[(u * 8 + v) * 32 + w];
            o0 += sM[ln][u * 9] * c;
        }
        out[n * 288 + w] = o0 * inv;
    }
    // l=1 block (96 floats at offset 32), layout [w][k], k<3
    {
        float o1[3] = {0.f, 0.f, 0.f};
        #pragma unroll
        for (int u = 0; u < 8; ++u) {
            float c = 0.f;
            #pragma unroll
            for (int v = 0; v < 8; ++v) c += a[v] * W3[(u * 8 + v) * 32 + w];
            #pragma unroll
            for (int k = 0; k < 3; ++k) o1[k] += sM[ln][u * 9 + 1 + k] * c;
        }
        #pragma unroll
        for (int k = 0; k < 3; ++k) out[n * 288 + 32 + w * 3 + k] = o1[k] * inv;
    }
    // l=2 block (160 floats at offset 128), layout [w][k], k<5
    {
        float o2[5] = {0.f, 0.f, 0.f, 0.f, 0.f};
        #pragma unroll
        for (int u = 0; u < 8; ++u) {
            float c = 0.f;
            #pragma unroll
            for (int v = 0; v < 8; ++v) c += a[v] * W9[(u * 8 + v) * 32 + w];
            #pragma unroll
            for (int k = 0; k < 5; ++k) o2[k] += sM[ln][u * 9 + 4 + k] * c;
        }
        #pragma unroll
        for (int k = 0; k < 5; ++k) out[n * 288 + 128 + w * 5 + k] = o2[k] * inv;
    }
}

// ---------------- launch ---------------------------------------------------------
extern "C" void kernel_launch(void* const* d_in, const int* in_sizes, int n_in,
                              void* d_out, int out_size, void* d_ws, size_t ws_size,
                              hipStream_t stream) {
    const float* pos         = (const float*)d_in[0];
    const float* edge_shifts = (const float*)d_in[1];
    const float* cell        = (const float*)d_in[2];
    const float* atom_emb    = (const float*)d_in[3];
    const float* mlp_w1      = (const float*)d_in[4];
    const float* mlp_b1      = (const float*)d_in[5];
    const float* mlp_w2      = (const float*)d_in[6];
    const float* mlp_b2      = (const float*)d_in[7];
    const float* fc_w1       = (const float*)d_in[8];
    const float* fc_b1       = (const float*)d_in[9];
    const float* fc_w2       = (const float*)d_in[10];
    const float* fc_b2       = (const float*)d_in[11];
    const float* fc_w3       = (const float*)d_in[12];
    const float* fc_b3       = (const float*)d_in[13];
    const float* tp_w        = (const float*)d_in[14];
    const int*   A           = (const int*)d_in[15];
    const int*   batch       = (const int*)d_in[16];
    const int*   edge_src    = (const int*)d_in[17];
    const int*   edge_dst    = (const int*)d_in[18];
    float* out = (float*)d_out;

    // workspace layout (16B aligned):
    // float4 elist[10000*128] | float Ai[80000] | float4 tab[TN+1] | int deg[10000]
    float4* elist = (float4*)d_ws;
    float*  Ai    = (float*)(elist + (size_t)N_NODES * CAP);
    float4* tab   = (float4*)(Ai + N_NODES * 8);
    int*    deg   = (int*)(tab + (TN + 1));
    // total: ~21 MB

    prep_kernel<<<AI_BLOCKS + TB_BLOCKS, 256, 0, stream>>>(
        atom_emb, A, mlp_w1, mlp_b1, mlp_w2, mlp_b2,
        fc_w1, fc_b1, fc_w2, fc_b2, fc_w3, fc_b3, Ai, tab, deg);

    bucket_kernel<<<N_EDGES / 256, 256, 0, stream>>>(
        edge_src, edge_dst, pos, edge_shifts, cell, batch, deg, elist);

    gather_out_kernel<<<N_NODES / 4, 256, 0, stream>>>(
        deg, elist, tab, Ai, tp_w, out);
}

// Round 13
// 152.641 us; speedup vs baseline: 1.8702x; 1.0221x over previous
//
#include <hip/hip_runtime.h>
#include <math.h>

#define N_NODES 10000
#define N_EDGES 320000
#define CAP 128        // max in-degree bucket capacity (mean 32, +17 sigma)
#define TN 8192        // gate table samples over [0, 8]; step = 1/1024
#define TSCALE 1024.0f // TN / 8
#define BK_BLOCKS 625  // 625*256*2 = 320000 edges, 2 edges/thread for ILP
#define TB_BLOCKS 2049 // ceil((TN+1)/4) wave-per-entry blocks
#define AI_BLOCKS 40   // 40*256 >= 10000 nodes

__device__ __forceinline__ float silu_f(float x) {
    return x / (1.0f + __expf(-x));
}

// ---------------- kernel 1 (fused): bucket + gates table + node Ai -------------
// Safe to fuse now (r7 lesson): every path's live state <= ~40 floats, no
// per-thread arrays -> no promote-alloca LDS, no spill at the allocator's
// 48-VGPR occupancy target. Bucket blocks first (latency-bound, overlaps the
// VALU-bound table build). deg[] cleared by a prior 40KB memset (race-free).
__global__ __launch_bounds__(256) void fused_prep_kernel(
    const int* __restrict__ edge_src, const int* __restrict__ edge_dst,
    const float* __restrict__ pos, const float* __restrict__ edge_shifts,
    const float* __restrict__ cell, const int* __restrict__ batch,
    const float* __restrict__ atom_emb, const int* __restrict__ A,
    const float* __restrict__ w1, const float* __restrict__ b1,
    const float* __restrict__ w2, const float* __restrict__ b2,
    const float* __restrict__ fw1, const float* __restrict__ fb1,
    const float* __restrict__ fw2, const float* __restrict__ fb2,
    const float* __restrict__ fw3, const float* __restrict__ fb3,
    float* __restrict__ Ai, float4* __restrict__ tab,
    int* __restrict__ deg, float4* __restrict__ elist)
{
    int bid = blockIdx.x;
    if (bid < BK_BLOCKS) {
        // ---- bucket insert, 2 independent edges per thread ----
        int e1 = bid * 256 + threadIdx.x;
        int e2 = e1 + (N_EDGES / 2);
        #pragma unroll
        for (int pass = 0; pass < 2; ++pass) {
            int e = pass ? e2 : e1;
            int dst = edge_dst[e];
            int src = edge_src[e];
            float s0 = edge_shifts[e * 3 + 0];
            float s1 = edge_shifts[e * 3 + 1];
            float s2 = edge_shifts[e * 3 + 2];
            float vx = pos[dst * 3 + 0] - pos[src * 3 + 0];
            float vy = pos[dst * 3 + 1] - pos[src * 3 + 1];
            float vz = pos[dst * 3 + 2] - pos[src * 3 + 2];
            if (s0 != 0.f || s1 != 0.f || s2 != 0.f) {  // wave-uniform false for zero shifts
                int b = batch[src];
                const float* Cb = cell + b * 9;
                vx += s0 * Cb[0] + s1 * Cb[3] + s2 * Cb[6];
                vy += s0 * Cb[1] + s1 * Cb[4] + s2 * Cb[7];
                vz += s0 * Cb[2] + s1 * Cb[5] + s2 * Cb[8];
            }
            int p = atomicAdd(&deg[dst], 1);
            if (p < CAP) elist[dst * CAP + p] = make_float4(vx, vy, vz, __int_as_float(src));
        }
        return;
    }
    if (bid < BK_BLOCKS + TB_BLOCKS) {
        // ---- gates(r) table: one wave per entry (r10 lesson: wave-parallel,
        // coalesced loads, shfl broadcast/reduce; no serial s_load chains) ----
        int lane = threadIdx.x & 63;
        int t = (bid - BK_BLOCKS) * 4 + (threadIdx.x >> 6);
        if (t > TN) return;
        float r = (float)t * (1.0f / TSCALE);

        float rb[10];
        {
            float x = r * 2.2f;
            #pragma unroll
            for (int i = 0; i < 10; ++i) {
                float d = x - (float)(i + 1);
                rb[i] = __expf(-d * d) * 2.8234622f;
            }
        }
        float g1;
        {
            float s = fb1[lane];
            #pragma unroll
            for (int k = 0; k < 10; ++k) s += rb[k] * fw1[k * 64 + lane];
            g1 = silu_f(s);
        }
        float acc = fb2[lane];
        #pragma unroll 8
        for (int i = 0; i < 64; ++i) {
            float gi = __shfl(g1, i, 64);
            acc += gi * fw2[i * 64 + lane];
        }
        float h = silu_f(acc);

        float p0 = h * fw3[lane * 15 + 0];
        float p3 = h * fw3[lane * 15 + 3];
        float p9 = h * fw3[lane * 15 + 9];
        #pragma unroll
        for (int m = 1; m < 64; m <<= 1) {
            p0 += __shfl_xor(p0, m, 64);
            p3 += __shfl_xor(p3, m, 64);
            p9 += __shfl_xor(p9, m, 64);
        }
        if (lane == 0) tab[t] = make_float4(fb3[0] + p0, fb3[3] + p3, fb3[9] + p9, 0.f);
        return;
    }

    // ---- node Ai = mlp(atom_emb[A]) ----
    int n = (bid - BK_BLOCKS - TB_BLOCKS) * 256 + threadIdx.x;
    if (n >= N_NODES) return;
    int a = A[n];
    float emb[16];
    #pragma unroll
    for (int i = 0; i < 16; ++i) emb[i] = atom_emb[a * 16 + i];
    float acc[8];
    #pragma unroll
    for (int o = 0; o < 8; ++o) acc[o] = b2[o];
    #pragma unroll 4
    for (int j = 0; j < 64; ++j) {
        float s0 = b1[j], s1 = 0.f;
        #pragma unroll
        for (int i = 0; i < 16; i += 2) {
            s0 += emb[i]     * w1[i * 64 + j];
            s1 += emb[i + 1] * w1[(i + 1) * 64 + j];
        }
        float h = silu_f(s0 + s1);
        #pragma unroll
        for (int o = 0; o < 8; ++o) acc[o] += h * w2[j * 8 + o];
    }
    #pragma unroll
    for (int o = 0; o < 8; ++o) Ai[n * 8 + o] = acc[o];
}

// ---------------- kernel 2: fused gather + tp_w contraction + output ------------
// Block = 256 threads = 4 waves = 4 nodes; lane = slot*8 + u.
// Edge loop unrolled x2 (two records in flight) to break the el[i] -> Ai[src]
// dependent-latency serialization.
__global__ __launch_bounds__(256) void gather_out_kernel(
    const int* __restrict__ deg, const float4* __restrict__ elist,
    const float4* __restrict__ tab, const float* __restrict__ Ai,
    const float* __restrict__ tp_w, float* __restrict__ out)
{
    __shared__ float sM[4][72];
    __shared__ float sA[4][8];
    int tid = threadIdx.x;
    int lane = tid & 63;
    int wv = tid >> 6;
    int nodeBase = blockIdx.x * 4;
    int n1 = nodeBase + wv;
    int u1 = lane & 7;
    int slot = lane >> 3;

    if (tid < 32) sA[tid >> 3][tid & 7] = Ai[nodeBase * 8 + tid];

    int d = deg[n1];
    int dc = d > CAP ? CAP : d;

    const float SQ3 = 1.7320508075688772f;
    const float SQ15 = 3.872983346207417f;
    const float SQ5H = 1.1180339887498949f;   // sqrt(5)/2

    float acc[9];
    #pragma unroll
    for (int k = 0; k < 9; ++k) acc[k] = 0.f;

    const float4* el = elist + n1 * CAP;

#define PROC(rec) do {                                                   \
        float vx = (rec).x, vy = (rec).y, vz = (rec).z;                  \
        int src = __float_as_int((rec).w);                               \
        float rr = sqrtf(vx * vx + vy * vy + vz * vz);                   \
        float rinv = 1.0f / fmaxf(rr, 1e-8f);                            \
        float nx = vx * rinv, ny = vy * rinv, nz = vz * rinv;            \
        float tf = fminf(rr * TSCALE, (float)(TN - 1));                  \
        int   i0 = (int)tf;                                              \
        float fr = tf - (float)i0;                                       \
        float4 ga = tab[i0];                                             \
        float4 gb = tab[i0 + 1];                                         \
        float gate0 = ga.x + fr * (gb.x - ga.x);                         \
        float gate3 = ga.y + fr * (gb.y - ga.y);                         \
        float gate9 = ga.z + fr * (gb.z - ga.z);                         \
        float au = Ai[src * 8 + u1];                                     \
        acc[0] += gate0 * au;                                            \
        float g3a = gate3 * au;                                          \
        acc[1] += g3a * (SQ3 * nx);                                      \
        acc[2] += g3a * (SQ3 * ny);                                      \
        acc[3] += g3a * (SQ3 * nz);                                      \
        float g9a = gate9 * au;                                          \
        acc[4] += g9a * (SQ15 * nx * ny);                                \
        acc[5] += g9a * (SQ15 * ny * nz);                                \
        acc[6] += g9a * (SQ5H * (3.0f * nz * nz - 1.0f));                \
        acc[7] += g9a * (SQ15 * nx * nz);                                \
        acc[8] += g9a * (0.5f * SQ15 * (nx * nx - ny * ny));             \
    } while (0)

    int i = slot;
    for (; i + 8 < dc; i += 16) {
        float4 r1 = el[i];
        float4 r2 = el[i + 8];
        PROC(r1);
        PROC(r2);
    }
    if (i < dc) {
        float4 r1 = el[i];
        PROC(r1);
    }
#undef PROC

    #pragma unroll
    for (int m = 8; m < 64; m <<= 1) {
        #pragma unroll
        for (int k = 0; k < 9; ++k) acc[k] += __shfl_xor(acc[k], m, 64);
    }

    if (slot == 0) {
        #pragma unroll
        for (int k = 0; k < 9; ++k) sM[wv][u1 * 9 + k] = acc[k];
    }
    __syncthreads();

    if (tid >= 128) return;
    int ln = tid >> 5, w = tid & 31;
    int n = nodeBase + ln;

    float a[8];
    #pragma unroll
    for (int v = 0; v < 8; ++v) a[v] = sA[ln][v];
    float inv = 1.0f / fmaxf((float)deg[n], 1.0f);

    const float* W0 = tp_w + 0 * 2048;   // path (0,0,0)
    const float* W3 = tp_w + 3 * 2048;   // path (1,0,1)
    const float* W9 = tp_w + 9 * 2048;   // path (2,0,2)

    // l=0 block (32 floats at offset 0)
    {
        float o0 = 0.f;
        #pragma unroll
        for (int u = 0; u < 8; ++u) {
            float c = 0.f;
            #pragma unroll
            for (int v = 0; v < 8; ++v) c += a[v] * W0[(u * 8 + v) * 32 + w];
            o0 += sM[ln][u * 9] * c;
        }
        out[n * 288 + w] = o0 * inv;
    }
    // l=1 block (96 floats at offset 32), layout [w][k], k<3
    {
        float o1[3] = {0.f, 0.f, 0.f};
        #pragma unroll
        for (int u = 0; u < 8; ++u) {
            float c = 0.f;
            #pragma unroll
            for (int v = 0; v < 8; ++v) c += a[v] * W3[(u * 8 + v) * 32 + w];
            #pragma unroll
            for (int k = 0; k < 3; ++k) o1[k] += sM[ln][u * 9 + 1 + k] * c;
        }
        #pragma unroll
        for (int k = 0; k < 3; ++k) out[n * 288 + 32 + w * 3 + k] = o1[k] * inv;
    }
    // l=2 block (160 floats at offset 128), layout [w][k], k<5
    {
        float o2[5] = {0.f, 0.f, 0.f, 0.f, 0.f};
        #pragma unroll
        for (int u = 0; u < 8; ++u) {
            float c = 0.f;
            #pragma unroll
            for (int v = 0; v < 8; ++v) c += a[v] * W9[(u * 8 + v) * 32 + w];
            #pragma unroll
            for (int k = 0; k < 5; ++k) o2[k] += sM[ln][u * 9 + 4 + k] * c;
        }
        #pragma unroll
        for (int k = 0; k < 5; ++k) out[n * 288 + 128 + w * 5 + k] = o2[k] * inv;
    }
}

// ---------------- launch ---------------------------------------------------------
extern "C" void kernel_launch(void* const* d_in, const int* in_sizes, int n_in,
                              void* d_out, int out_size, void* d_ws, size_t ws_size,
                              hipStream_t stream) {
    const float* pos         = (const float*)d_in[0];
    const float* edge_shifts = (const float*)d_in[1];
    const float* cell        = (const float*)d_in[2];
    const float* atom_emb    = (const float*)d_in[3];
    const float* mlp_w1      = (const float*)d_in[4];
    const float* mlp_b1      = (const float*)d_in[5];
    const float* mlp_w2      = (const float*)d_in[6];
    const float* mlp_b2      = (const float*)d_in[7];
    const float* fc_w1       = (const float*)d_in[8];
    const float* fc_b1       = (const float*)d_in[9];
    const float* fc_w2       = (const float*)d_in[10];
    const float* fc_b2       = (const float*)d_in[11];
    const float* fc_w3       = (const float*)d_in[12];
    const float* fc_b3       = (const float*)d_in[13];
    const float* tp_w        = (const float*)d_in[14];
    const int*   A           = (const int*)d_in[15];
    const int*   batch       = (const int*)d_in[16];
    const int*   edge_src    = (const int*)d_in[17];
    const int*   edge_dst    = (const int*)d_in[18];
    float* out = (float*)d_out;

    // workspace layout (16B aligned):
    // float4 elist[10000*128] | float Ai[80000] | float4 tab[TN+1] | int deg[10000]
    float4* elist = (float4*)d_ws;
    float*  Ai    = (float*)(elist + (size_t)N_NODES * CAP);
    float4* tab   = (float4*)(Ai + N_NODES * 8);
    int*    deg   = (int*)(tab + (TN + 1));
    // total: ~21 MB

    hipMemsetAsync(deg, 0, N_NODES * sizeof(int), stream);

    fused_prep_kernel<<<BK_BLOCKS + TB_BLOCKS + AI_BLOCKS, 256, 0, stream>>>(
        edge_src, edge_dst, pos, edge_shifts, cell, batch,
        atom_emb, A, mlp_w1, mlp_b1, mlp_w2, mlp_b2,
        fc_w1, fc_b1, fc_w2, fc_b2, fc_w3, fc_b3, Ai, tab, deg, elist);

    gather_out_kernel<<<N_NODES / 4, 256, 0, stream>>>(
        deg, elist, tab, Ai, tp_w, out);
}